// Round 7
// baseline (1145.533 us; speedup 1.0000x reference)
//
#include <hip/hip_runtime.h>

namespace {

constexpr int kS = 1024;
constexpr int kD = 64;
constexpr int kH = 128;

typedef __attribute__((ext_vector_type(2))) _Float16 half2v;
typedef __attribute__((ext_vector_type(4))) float f32x4;
typedef __attribute__((ext_vector_type(8))) _Float16 half8;

__device__ __forceinline__ float fdot2(unsigned w, unsigned h, float acc) {
#if __has_builtin(__builtin_amdgcn_fdot2)
  return __builtin_amdgcn_fdot2(__builtin_bit_cast(half2v, w),
                                __builtin_bit_cast(half2v, h), acc, false);
#else
  float d;
  asm("v_dot2_f32_f16 %0, %1, %2, %3" : "=v"(d) : "v"(w), "v"(h), "v"(acc));
  return d;
#endif
}

// RNE f16 pack
__device__ __forceinline__ unsigned pk16(float a, float b) {
  half2v h;
  h.x = (_Float16)a;
  h.y = (_Float16)b;
  return __builtin_bit_cast(unsigned, h);
}

// tanh(x) = 1 - 2/(e^{2x}+1). No clamp needed: e->inf gives 1, e->0 gives -1.
__device__ __forceinline__ float fast_tanh(float x) {
  float e = __expf(2.f * x);
  return fmaf(-2.f, __builtin_amdgcn_rcpf(e + 1.f), 1.f);
}

#if __has_builtin(__builtin_amdgcn_mov_dpp)
__device__ __forceinline__ float lane_xor1(float v) {
  return __int_as_float(__builtin_amdgcn_mov_dpp(__float_as_int(v), 0xB1, 0xF, 0xF, true));
}
#else
__device__ __forceinline__ float lane_xor1(float v) {
  return __int_as_float(__builtin_amdgcn_ds_swizzle(__float_as_int(v), 0x041F));
}
#endif

// async global->LDS: 8 x 16B/lane = one 8 KB xp chunk
__device__ __forceinline__ void stage_chunk(const char* g, unsigned* lds, int L) {
#pragma unroll
  for (int k = 0; k < 8; ++k) {
    __builtin_amdgcn_global_load_lds(
        (const __attribute__((address_space(1))) void*)(g + k * 1024 + L * 16),
        (__attribute__((address_space(3))) void*)(lds + k * 256), 16, 0, 0);
  }
}

// xp (f16) layout per (dir,b) slab: idx = (t>>5)*(32*kH) + (t&31)*kH + j
// (dir=1 pre-time-reversed) -> one 32-step chunk = 8 KB contiguous.

// =====================  Phase A: x-projection via f16 MFMA (unchanged, 84 us) ==
__global__ __launch_bounds__(256, 2) void xproj_kernel(
    const float* __restrict__ inputs,
    const float* __restrict__ Wih_fw, const float* __restrict__ bih_fw,
    const float* __restrict__ bhh_fw,
    const float* __restrict__ Wih_bw, const float* __restrict__ bih_bw,
    const float* __restrict__ bhh_bw,
    _Float16* __restrict__ xp) {
  __shared__ _Float16 Wl[256 * 80];
  __shared__ _Float16 xl[128 * 80];
  __shared__ float biasl[256];

  const int tid = threadIdx.x;
  const int b = blockIdx.x;
  const int w = tid >> 6;
  const int lane = tid & 63;
  const int n16 = lane & 15;
  const int q = lane >> 4;

  {
    const int jd = tid;
    const float* src = (jd < kH) ? (Wih_fw + jd * kD) : (Wih_bw + (jd - kH) * kD);
    const float4* s4 = (const float4*)src;
#pragma unroll
    for (int k = 0; k < 8; ++k) {
      float4 a = s4[2 * k], c = s4[2 * k + 1];
      half8 h;
      h[0] = (_Float16)a.x; h[1] = (_Float16)a.y; h[2] = (_Float16)a.z; h[3] = (_Float16)a.w;
      h[4] = (_Float16)c.x; h[5] = (_Float16)c.y; h[6] = (_Float16)c.z; h[7] = (_Float16)c.w;
      *(half8*)&Wl[jd * 80 + k * 8] = h;
    }
    biasl[jd] = (jd < kH) ? (bih_fw[jd] + bhh_fw[jd])
                          : (bih_bw[jd - kH] + bhh_bw[jd - kH]);
  }

  for (int ch = 0; ch < 8; ++ch) {
    __syncthreads();
    {
      const int tl = tid >> 1, hf = tid & 1;
      const float4* s4 = (const float4*)(inputs +
          ((size_t)b * kS + ch * 128 + tl) * kD + hf * 32);
#pragma unroll
      for (int k = 0; k < 4; ++k) {
        float4 a = s4[2 * k], c = s4[2 * k + 1];
        half8 h;
        h[0] = (_Float16)a.x; h[1] = (_Float16)a.y; h[2] = (_Float16)a.z; h[3] = (_Float16)a.w;
        h[4] = (_Float16)c.x; h[5] = (_Float16)c.y; h[6] = (_Float16)c.z; h[7] = (_Float16)c.w;
        *(half8*)&xl[tl * 80 + hf * 32 + k * 8] = h;
      }
    }
    __syncthreads();

    half8 bf0[4], bf1[4];
    float bs[4];
#pragma unroll
    for (int nn = 0; nn < 4; ++nn) {
      const int jd = (w * 4 + nn) * 16 + n16;
      bf0[nn] = *(const half8*)&Wl[jd * 80 + q * 8];
      bf1[nn] = *(const half8*)&Wl[jd * 80 + q * 8 + 32];
      bs[nn] = biasl[jd];
    }

#pragma unroll 2
    for (int m = 0; m < 8; ++m) {
      const int trow = m * 16 + n16;
      const half8 a0 = *(const half8*)&xl[trow * 80 + q * 8];
      const half8 a1 = *(const half8*)&xl[trow * 80 + q * 8 + 32];
#pragma unroll
      for (int nn = 0; nn < 4; ++nn) {
        f32x4 acc = {0.f, 0.f, 0.f, 0.f};
        acc = __builtin_amdgcn_mfma_f32_16x16x32_f16(a0, bf0[nn], acc, 0, 0, 0);
        acc = __builtin_amdgcn_mfma_f32_16x16x32_f16(a1, bf1[nn], acc, 0, 0, 0);
        const int jd = (w * 4 + nn) * 16 + n16;
        const int dir = jd >> 7, j = jd & 127;
        const size_t slab = (size_t)(dir * 256 + b) * (kS * kH);
#pragma unroll
        for (int r = 0; r < 4; ++r) {
          const int t = ch * 128 + m * 16 + q * 4 + r;
          const int tt = dir ? (kS - 1 - t) : t;
          xp[slab + (size_t)(tt >> 5) * (32 * kH) + (tt & 31) * kH + j] =
              (_Float16)(acc[r] + bs[nn]);
        }
      }
    }
  }
}

// =====================  Phase B: 2 recurrences per wave  =====================
// 256 blocks x 64 threads (ONE wave): dir = bi>>7, rows b0=2*(bi&127), b0+1.
// Both rows share dir => SAME Whh => same 128 weight dwords. Lane L owns
// j0=2L, j1=2L+1 full-K for BOTH rows: per step 2x(16 uniform b128 + 128 dot2);
// row B's dots fill row A's LDS-latency stalls. Ring rows have compile-time ds
// offsets (4-step groups). No barriers (single wave, DS is in-order per wave).
__global__ __launch_bounds__(64, 1) void birnn_step_kernel(
    const _Float16* __restrict__ xp,
    const float* __restrict__ Whh_fw, const float* __restrict__ Whh_bw,
    const float* __restrict__ fcW, const float* __restrict__ fcb,
    float* __restrict__ out) {
  const int dir = blockIdx.x >> 7;
  const int b0 = (blockIdx.x & 127) * 2;
  const int L = threadIdx.x;

  __shared__ unsigned jrn[32 * 136];     // [s][rowA 64dw | pad4 | rowB 64dw | pad4]
  __shared__ unsigned xbuf[2][2][2048];  // [row][buf][8KB chunk]
  __shared__ unsigned fcwl[64];
  __shared__ float outbuf[2][kS];

  const float* __restrict__ Whh = dir ? Whh_bw : Whh_fw;

  // ---- weights: rows j0=2L, j1=2L+1 -> 128 packed-f16 dwords ----
  unsigned w0[64], w1[64];
  {
    const float4* r0 = (const float4*)(Whh + (size_t)(2 * L) * kH);
    const float4* r1 = (const float4*)(Whh + (size_t)(2 * L + 1) * kH);
#pragma unroll
    for (int k = 0; k < 32; ++k) {
      const float4 v0 = r0[k], v1 = r1[k];
      w0[2 * k + 0] = pk16(v0.x, v0.y);
      w0[2 * k + 1] = pk16(v0.z, v0.w);
      w1[2 * k + 0] = pk16(v1.x, v1.y);
      w1[2 * k + 1] = pk16(v1.z, v1.w);
    }
  }
  fcwl[L] = pk16(fcW[dir * kH + 2 * L], fcW[dir * kH + 2 * L + 1]);
  jrn[31 * 136 + L] = 0;       // h_{-1} = 0, row A
  jrn[31 * 136 + 68 + L] = 0;  // row B

  const char* slabA = (const char*)(xp + (size_t)(dir * 256 + b0) * (kS * kH));
  const char* slabB = (const char*)(xp + (size_t)(dir * 256 + b0 + 1) * (kS * kH));
  stage_chunk(slabA, &xbuf[0][0][0], L);
  stage_chunk(slabB, &xbuf[1][0][0], L);
  stage_chunk(slabA + 8192, &xbuf[0][1][0], L);
  stage_chunk(slabB + 8192, &xbuf[1][1][0], L);
  asm volatile("s_waitcnt vmcnt(0)" ::: "memory");

  for (int c = 0; c < 32; ++c) {
    const unsigned* xbA = &xbuf[0][c & 1][0];
    const unsigned* xbB = &xbuf[1][c & 1][0];

    for (int g = 0; g < 8; ++g) {  // 8 groups x 4 steps: imm ds offsets
      const uint4* bw = (const uint4*)&jrn[g * 4 * 136];
      const uint4* br = (g == 0) ? (const uint4*)&jrn[31 * 136]
                                 : (const uint4*)&jrn[(g * 4 - 1) * 136];
#pragma unroll
      for (int u = 0; u < 4; ++u) {
        const int s = g * 4 + u;
        const uint4* hA = (u == 0) ? br : (bw + (u - 1) * 34);
        const uint4* hB = hA + 17;  // +68 dwords

        float a0 = 0.f, a1 = 0.f, a2 = 0.f, a3 = 0.f;  // row A, j0
        float d0 = 0.f, d1 = 0.f, d2 = 0.f, d3 = 0.f;  // row A, j1
        float e0 = 0.f, e1 = 0.f, e2 = 0.f, e3 = 0.f;  // row B, j0
        float f0 = 0.f, f1 = 0.f, f2 = 0.f, f3 = 0.f;  // row B, j1
#pragma unroll
        for (int g2 = 0; g2 < 16; ++g2) {
          const uint4 vA = hA[g2];
          const uint4 vB = hB[g2];
          a0 = fdot2(w0[4 * g2 + 0], vA.x, a0);
          d0 = fdot2(w1[4 * g2 + 0], vA.x, d0);
          e0 = fdot2(w0[4 * g2 + 0], vB.x, e0);
          f0 = fdot2(w1[4 * g2 + 0], vB.x, f0);
          a1 = fdot2(w0[4 * g2 + 1], vA.y, a1);
          d1 = fdot2(w1[4 * g2 + 1], vA.y, d1);
          e1 = fdot2(w0[4 * g2 + 1], vB.y, e1);
          f1 = fdot2(w1[4 * g2 + 1], vB.y, f1);
          a2 = fdot2(w0[4 * g2 + 2], vA.z, a2);
          d2 = fdot2(w1[4 * g2 + 2], vA.z, d2);
          e2 = fdot2(w0[4 * g2 + 2], vB.z, e2);
          f2 = fdot2(w1[4 * g2 + 2], vB.z, f2);
          a3 = fdot2(w0[4 * g2 + 3], vA.w, a3);
          d3 = fdot2(w1[4 * g2 + 3], vA.w, d3);
          e3 = fdot2(w0[4 * g2 + 3], vB.w, e3);
          f3 = fdot2(w1[4 * g2 + 3], vB.w, f3);
        }
        const half2v xA = __builtin_bit_cast(half2v, xbA[s * 64 + L]);
        const half2v xB = __builtin_bit_cast(half2v, xbB[s * 64 + L]);
        const float vAa = ((a0 + a1) + (a2 + a3)) + (float)xA.x;
        const float vAd = ((d0 + d1) + (d2 + d3)) + (float)xA.y;
        const float vBe = ((e0 + e1) + (e2 + e3)) + (float)xB.x;
        const float vBf = ((f0 + f1) + (f2 + f3)) + (float)xB.y;
        jrn[s * 136 + L] = pk16(fast_tanh(vAa), fast_tanh(vAd));
        jrn[s * 136 + 68 + L] = pk16(fast_tanh(vBe), fast_tanh(vBf));
      }
    }

    // ---- issue DMA for chunk c+2 early (overlaps drain + next steps) ----
    if (c < 30) {
      stage_chunk(slabA + (size_t)(c + 2) * 8192, &xbuf[0][c & 1][0], L);
      stage_chunk(slabB + (size_t)(c + 2) * 8192, &xbuf[1][c & 1][0], L);
    }

    // ---- fc drain of chunk c (both rows) ----
    {
      const int tl = L >> 1, jh = L & 1;
      const uint4* fp = (const uint4*)&fcwl[jh * 32];
      const uint4* rpA = (const uint4*)&jrn[tl * 136 + jh * 32];
      const uint4* rpB = (const uint4*)&jrn[tl * 136 + 68 + jh * 32];
      float accA = 0.f, accB = 0.f;
#pragma unroll
      for (int k = 0; k < 8; ++k) {
        const uint4 fw = fp[k];
        const uint4 hA = rpA[k];
        const uint4 hB = rpB[k];
        accA = fdot2(fw.x, hA.x, accA);
        accB = fdot2(fw.x, hB.x, accB);
        accA = fdot2(fw.y, hA.y, accA);
        accB = fdot2(fw.y, hB.y, accB);
        accA = fdot2(fw.z, hA.z, accA);
        accB = fdot2(fw.z, hB.z, accB);
        accA = fdot2(fw.w, hA.w, accA);
        accB = fdot2(fw.w, hB.w, accB);
      }
      accA += lane_xor1(accA);
      accB += lane_xor1(accB);
      if (jh == 0) {
        outbuf[0][c * 32 + tl] = accA;
        outbuf[1][c * 32 + tl] = accB;
      }
    }

    if (c < 30) {
      asm volatile("s_waitcnt vmcnt(16)" ::: "memory");  // chunk c+1 landed
    } else if (c == 30) {
      asm volatile("s_waitcnt vmcnt(0)" ::: "memory");
    }
  }

  // ---- emit (single atomic pass; fw adds fcb) ----
  const float fcb0 = (dir == 0) ? fcb[0] : 0.f;
#pragma unroll
  for (int k = 0; k < 16; ++k) {
    const int t = L + 64 * k;
    const int td = dir ? (kS - 1 - t) : t;
    atomicAdd(&out[(size_t)b0 * kS + td], outbuf[0][t] + fcb0);
    atomicAdd(&out[(size_t)(b0 + 1) * kS + td], outbuf[1][t] + fcb0);
  }
}

}  // namespace

extern "C" void kernel_launch(void* const* d_in, const int* in_sizes, int n_in,
                              void* d_out, int out_size, void* d_ws, size_t ws_size,
                              hipStream_t stream) {
  (void)in_sizes; (void)n_in; (void)ws_size;
  const float* inputs = (const float*)d_in[0];
  const float* Wih_fw = (const float*)d_in[1];
  const float* Whh_fw = (const float*)d_in[2];
  const float* bih_fw = (const float*)d_in[3];
  const float* bhh_fw = (const float*)d_in[4];
  const float* Wih_bw = (const float*)d_in[5];
  const float* Whh_bw = (const float*)d_in[6];
  const float* bih_bw = (const float*)d_in[7];
  const float* bhh_bw = (const float*)d_in[8];
  const float* fc_W   = (const float*)d_in[9];
  const float* fc_b   = (const float*)d_in[10];
  float* out = (float*)d_out;
  _Float16* xpw = (_Float16*)d_ws;  // 128 MiB

  hipMemsetAsync(out, 0, (size_t)out_size * sizeof(float), stream);

  hipLaunchKernelGGL(xproj_kernel, dim3(256), dim3(256), 0, stream,
                     inputs, Wih_fw, bih_fw, bhh_fw, Wih_bw, bih_bw, bhh_bw, xpw);
  hipLaunchKernelGGL(birnn_step_kernel, dim3(256), dim3(64), 0, stream,
                     xpw, Whh_fw, Whh_bw, fc_W, fc_b, out);
}

// Round 8
// 1056.658 us; speedup vs baseline: 1.0841x; 1.0841x over previous
//
#include <hip/hip_runtime.h>

namespace {

constexpr int kS = 1024;
constexpr int kD = 64;
constexpr int kH = 128;

typedef __attribute__((ext_vector_type(2))) _Float16 half2v;
typedef __attribute__((ext_vector_type(4))) float f32x4;
typedef __attribute__((ext_vector_type(8))) _Float16 half8;

__device__ __forceinline__ float fdot2(unsigned w, unsigned h, float acc) {
#if __has_builtin(__builtin_amdgcn_fdot2)
  return __builtin_amdgcn_fdot2(__builtin_bit_cast(half2v, w),
                                __builtin_bit_cast(half2v, h), acc, false);
#else
  float d;
  asm("v_dot2_f32_f16 %0, %1, %2, %3" : "=v"(d) : "v"(w), "v"(h), "v"(acc));
  return d;
#endif
}

__device__ __forceinline__ unsigned pk16(float a, float b) {  // RNE f16 pack
  half2v h;
  h.x = (_Float16)a;
  h.y = (_Float16)b;
  return __builtin_bit_cast(unsigned, h);
}

// tanh(x) = 1 - 2/(e^{2x}+1); e->inf saturates to 1, e->0 to -1.
__device__ __forceinline__ float fast_tanh(float x) {
  float e = __expf(2.f * x);
  return fmaf(-2.f, __builtin_amdgcn_rcpf(e + 1.f), 1.f);
}

// lgkm-only barrier: does NOT drain vmcnt (keeps global prefetch in flight).
__device__ __forceinline__ void wave_barrier() {
  asm volatile("s_waitcnt lgkmcnt(0)\n\ts_barrier" ::: "memory");
}

// xp (f16) global layout: slab = dir*16 + (b>>4); within slab:
//   addr = (t*16 + (b&15))*128 + j      (dir=1 pre-time-reversed)
// -> one 4-step chunk = 16 KB contiguous (1024 uint4), register-stageable.

// =====================  Phase A: x-projection via f16 MFMA  =====================
__global__ __launch_bounds__(256, 2) void xproj_kernel(
    const float* __restrict__ inputs,
    const float* __restrict__ Wih_fw, const float* __restrict__ bih_fw,
    const float* __restrict__ bhh_fw,
    const float* __restrict__ Wih_bw, const float* __restrict__ bih_bw,
    const float* __restrict__ bhh_bw,
    _Float16* __restrict__ xp) {
  __shared__ _Float16 Wl[256 * 80];
  __shared__ _Float16 xl[128 * 80];
  __shared__ float biasl[256];

  const int tid = threadIdx.x;
  const int b = blockIdx.x;
  const int w = tid >> 6;
  const int lane = tid & 63;
  const int n16 = lane & 15;
  const int q = lane >> 4;

  {
    const int jd = tid;
    const float* src = (jd < kH) ? (Wih_fw + jd * kD) : (Wih_bw + (jd - kH) * kD);
    const float4* s4 = (const float4*)src;
#pragma unroll
    for (int k = 0; k < 8; ++k) {
      float4 a = s4[2 * k], c = s4[2 * k + 1];
      half8 h;
      h[0] = (_Float16)a.x; h[1] = (_Float16)a.y; h[2] = (_Float16)a.z; h[3] = (_Float16)a.w;
      h[4] = (_Float16)c.x; h[5] = (_Float16)c.y; h[6] = (_Float16)c.z; h[7] = (_Float16)c.w;
      *(half8*)&Wl[jd * 80 + k * 8] = h;
    }
    biasl[jd] = (jd < kH) ? (bih_fw[jd] + bhh_fw[jd])
                          : (bih_bw[jd - kH] + bhh_bw[jd - kH]);
  }

  const int gb = b >> 4, ncol = b & 15;

  for (int ch = 0; ch < 8; ++ch) {
    __syncthreads();
    {
      const int tl = tid >> 1, hf = tid & 1;
      const float4* s4 = (const float4*)(inputs +
          ((size_t)b * kS + ch * 128 + tl) * kD + hf * 32);
#pragma unroll
      for (int k = 0; k < 4; ++k) {
        float4 a = s4[2 * k], c = s4[2 * k + 1];
        half8 h;
        h[0] = (_Float16)a.x; h[1] = (_Float16)a.y; h[2] = (_Float16)a.z; h[3] = (_Float16)a.w;
        h[4] = (_Float16)c.x; h[5] = (_Float16)c.y; h[6] = (_Float16)c.z; h[7] = (_Float16)c.w;
        *(half8*)&xl[tl * 80 + hf * 32 + k * 8] = h;
      }
    }
    __syncthreads();

    half8 bf0[4], bf1[4];
    float bs[4];
#pragma unroll
    for (int nn = 0; nn < 4; ++nn) {
      const int jd = (w * 4 + nn) * 16 + n16;
      bf0[nn] = *(const half8*)&Wl[jd * 80 + q * 8];
      bf1[nn] = *(const half8*)&Wl[jd * 80 + q * 8 + 32];
      bs[nn] = biasl[jd];
    }

#pragma unroll 2
    for (int m = 0; m < 8; ++m) {
      const int trow = m * 16 + n16;
      const half8 a0 = *(const half8*)&xl[trow * 80 + q * 8];
      const half8 a1 = *(const half8*)&xl[trow * 80 + q * 8 + 32];
#pragma unroll
      for (int nn = 0; nn < 4; ++nn) {
        f32x4 acc = {0.f, 0.f, 0.f, 0.f};
        acc = __builtin_amdgcn_mfma_f32_16x16x32_f16(a0, bf0[nn], acc, 0, 0, 0);
        acc = __builtin_amdgcn_mfma_f32_16x16x32_f16(a1, bf1[nn], acc, 0, 0, 0);
        const int jd = (w * 4 + nn) * 16 + n16;
        const int dirx = jd >> 7, j = jd & 127;
        const size_t slab = (size_t)(dirx * 16 + gb) * (kS * 2048);
#pragma unroll
        for (int r = 0; r < 4; ++r) {
          const int t = ch * 128 + m * 16 + q * 4 + r;
          const int tt = dirx ? (kS - 1 - t) : t;
          xp[slab + ((size_t)tt * 16 + ncol) * 128 + j] = (_Float16)(acc[r] + bs[nn]);
        }
      }
    }
  }
}

// =====================  Phase B: MFMA-batched recurrence  =====================
// 32 blocks x 128 threads (2 waves): dir = bi>>4, batch group g = bi&15 (16 b).
// Per step: D[128][16] = Whh(A-frags, reg/AGPR-resident) x H(B-frags from LDS
// ring) + xp (C-init). Wave w owns M-tiles 4w..4w+3 (4 indep K-chains of 4).
// Ring rows pitch 68 dw (b128-aligned, bank-balanced); ring = fc journal,
// drained every 4 steps. Barriers are lgkm-only (prefetch stays in flight).
__global__ __launch_bounds__(128, 1) void birnn_mfma_kernel(
    const _Float16* __restrict__ xp,
    const float* __restrict__ Whh_fw, const float* __restrict__ Whh_bw,
    const float* __restrict__ fcW, const float* __restrict__ fcb,
    float* __restrict__ out) {
  const int dir = blockIdx.x >> 4;
  const int g = blockIdx.x & 15;
  const int tid = threadIdx.x;
  const int w = tid >> 6;
  const int lane = tid & 63;
  const int n = lane & 15;   // A: m-index; B: batch col; D: col
  const int q = lane >> 4;

  __shared__ unsigned ring[8 * 1088];     // [slot][n][kpair], pitch 68
  __shared__ unsigned xbuf[2][4 * 1088];  // staged xp chunks, same padding
  __shared__ unsigned fcl[64];            // fc weights, packed f16 kpairs

  const float* __restrict__ Whh = dir ? Whh_bw : Whh_fw;
  const float fcb0 = fcb[0];

  // ---- A-frags: af[ml][kt] = Whh[j=64w+16ml+n][k=32kt+8q+e], e=0..7 ----
  half8 af[4][4];
#pragma unroll
  for (int ml = 0; ml < 4; ++ml)
#pragma unroll
    for (int kt = 0; kt < 4; ++kt) {
      const float4* src =
          (const float4*)(Whh + (size_t)(64 * w + 16 * ml + n) * kH + 32 * kt + 8 * q);
      const float4 aa = src[0], bb = src[1];
      half8 h;
      h[0] = (_Float16)aa.x; h[1] = (_Float16)aa.y; h[2] = (_Float16)aa.z; h[3] = (_Float16)aa.w;
      h[4] = (_Float16)bb.x; h[5] = (_Float16)bb.y; h[6] = (_Float16)bb.z; h[7] = (_Float16)bb.w;
      af[ml][kt] = h;
    }
  if (tid < 64) fcl[tid] = pk16(fcW[dir * kH + 2 * tid], fcW[dir * kH + 2 * tid + 1]);
#pragma unroll
  for (int k = 0; k < 9; ++k) {  // zero ring slot 7 (h_{-1} = 0)
    const int idx = tid + 128 * k;
    if (idx < 1088) ring[7 * 1088 + idx] = 0;
  }

  // ---- xp chunk staging (register prefetch, 2 chunks ahead) ----
  const uint4* gx = (const uint4*)(xp + (size_t)(dir * 16 + g) * (kS * 2048));
  uint4 rv[8];
#pragma unroll
  for (int k = 0; k < 8; ++k) rv[k] = gx[tid + 128 * k];  // chunk 0
#pragma unroll
  for (int k = 0; k < 8; ++k) {
    const int idx = tid + 128 * k;
    const int t_loc = idx >> 8, rem = idx & 255, nn = rem >> 4, q4 = rem & 15;
    *(uint4*)&xbuf[0][t_loc * 1088 + nn * 68 + 4 * q4] = rv[k];
  }
#pragma unroll
  for (int k = 0; k < 8; ++k) rv[k] = gx[1024 + tid + 128 * k];  // chunk 1 held
  wave_barrier();

  for (int c = 0; c < 256; ++c) {
    const int cur = c & 1;
    if (c < 255) {  // stage held chunk c+1 (buffer last read during c-1)
#pragma unroll
      for (int k = 0; k < 8; ++k) {
        const int idx = tid + 128 * k;
        const int t_loc = idx >> 8, rem = idx & 255, nn = rem >> 4, q4 = rem & 15;
        *(uint4*)&xbuf[cur ^ 1][t_loc * 1088 + nn * 68 + 4 * q4] = rv[k];
      }
    }
    if (c < 254) {  // issue loads for chunk c+2
#pragma unroll
      for (int k = 0; k < 8; ++k) rv[k] = gx[(size_t)(c + 2) * 1024 + tid + 128 * k];
    }
    if (c > 0 && lane < 32) {  // fc drain of chunk c-1 (slots 4*(cur^1)+0..3)
      const int t_loc = 2 * w + (lane >> 4);
      const int dn = lane & 15;
      const int slot = 4 * (cur ^ 1) + t_loc;
      const uint4* hr = (const uint4*)&ring[slot * 1088 + dn * 68];
      const uint4* fp = (const uint4*)fcl;
      float s = 0.f;
#pragma unroll
      for (int k2 = 0; k2 < 16; ++k2) {
        const uint4 h = hr[k2], f = fp[k2];
        s = fdot2(f.x, h.x, s);
        s = fdot2(f.y, h.y, s);
        s = fdot2(f.z, h.z, s);
        s = fdot2(f.w, h.w, s);
      }
      const int t = (c - 1) * 4 + t_loc;
      const int td = dir ? (kS - 1 - t) : t;
      atomicAdd(&out[(size_t)(g * 16 + dn) * kS + td], s + (dir == 0 ? fcb0 : 0.f));
    }

#pragma unroll
    for (int tl = 0; tl < 4; ++tl) {
      const int wslot = cur * 4 + tl;
      const int rslot = (wslot + 7) & 7;
      const uint4* hrow = (const uint4*)&ring[rslot * 1088 + n * 68];
      const half8 bf0 = __builtin_bit_cast(half8, hrow[q]);
      const half8 bf1 = __builtin_bit_cast(half8, hrow[4 + q]);
      const half8 bf2 = __builtin_bit_cast(half8, hrow[8 + q]);
      const half8 bf3 = __builtin_bit_cast(half8, hrow[12 + q]);

      const unsigned* xb = &xbuf[cur][tl * 1088 + n * 68];
      f32x4 acc[4];
#pragma unroll
      for (int ml = 0; ml < 4; ++ml) {  // C init = xp (D = Whh*h + xp)
        const uint2 xv = *(const uint2*)&xb[8 * (4 * w + ml) + 2 * q];
        const half2v x0 = __builtin_bit_cast(half2v, xv.x);
        const half2v x1 = __builtin_bit_cast(half2v, xv.y);
        f32x4 a;
        a[0] = (float)x0.x; a[1] = (float)x0.y; a[2] = (float)x1.x; a[3] = (float)x1.y;
        acc[ml] = a;
      }
#pragma unroll
      for (int ml = 0; ml < 4; ++ml)
        acc[ml] = __builtin_amdgcn_mfma_f32_16x16x32_f16(af[ml][0], bf0, acc[ml], 0, 0, 0);
#pragma unroll
      for (int ml = 0; ml < 4; ++ml)
        acc[ml] = __builtin_amdgcn_mfma_f32_16x16x32_f16(af[ml][1], bf1, acc[ml], 0, 0, 0);
#pragma unroll
      for (int ml = 0; ml < 4; ++ml)
        acc[ml] = __builtin_amdgcn_mfma_f32_16x16x32_f16(af[ml][2], bf2, acc[ml], 0, 0, 0);
#pragma unroll
      for (int ml = 0; ml < 4; ++ml)
        acc[ml] = __builtin_amdgcn_mfma_f32_16x16x32_f16(af[ml][3], bf3, acc[ml], 0, 0, 0);

#pragma unroll
      for (int ml = 0; ml < 4; ++ml) {  // tanh + pack + journal write
        const float t0 = fast_tanh(acc[ml][0]);
        const float t1 = fast_tanh(acc[ml][1]);
        const float t2 = fast_tanh(acc[ml][2]);
        const float t3 = fast_tanh(acc[ml][3]);
        uint2 o;
        o.x = pk16(t0, t1);
        o.y = pk16(t2, t3);
        *(uint2*)&ring[wslot * 1088 + n * 68 + 8 * (4 * w + ml) + 2 * q] = o;
      }
      wave_barrier();
    }
  }

  // ---- final fc drain: chunk 255 (slots 4..7) ----
  if (lane < 32) {
    const int t_loc = 2 * w + (lane >> 4);
    const int dn = lane & 15;
    const int slot = 4 + t_loc;
    const uint4* hr = (const uint4*)&ring[slot * 1088 + dn * 68];
    const uint4* fp = (const uint4*)fcl;
    float s = 0.f;
#pragma unroll
    for (int k2 = 0; k2 < 16; ++k2) {
      const uint4 h = hr[k2], f = fp[k2];
      s = fdot2(f.x, h.x, s);
      s = fdot2(f.y, h.y, s);
      s = fdot2(f.z, h.z, s);
      s = fdot2(f.w, h.w, s);
    }
    const int t = 255 * 4 + t_loc;
    const int td = dir ? (kS - 1 - t) : t;
    atomicAdd(&out[(size_t)(g * 16 + dn) * kS + td], s + (dir == 0 ? fcb0 : 0.f));
  }
}

}  // namespace

extern "C" void kernel_launch(void* const* d_in, const int* in_sizes, int n_in,
                              void* d_out, int out_size, void* d_ws, size_t ws_size,
                              hipStream_t stream) {
  (void)in_sizes; (void)n_in; (void)ws_size;
  const float* inputs = (const float*)d_in[0];
  const float* Wih_fw = (const float*)d_in[1];
  const float* Whh_fw = (const float*)d_in[2];
  const float* bih_fw = (const float*)d_in[3];
  const float* bhh_fw = (const float*)d_in[4];
  const float* Wih_bw = (const float*)d_in[5];
  const float* Whh_bw = (const float*)d_in[6];
  const float* bih_bw = (const float*)d_in[7];
  const float* bhh_bw = (const float*)d_in[8];
  const float* fc_W   = (const float*)d_in[9];
  const float* fc_b   = (const float*)d_in[10];
  float* out = (float*)d_out;
  _Float16* xpw = (_Float16*)d_ws;  // 32 slabs * 1024 * 2048 f16 = 128 MiB

  hipMemsetAsync(out, 0, (size_t)out_size * sizeof(float), stream);

  hipLaunchKernelGGL(xproj_kernel, dim3(256), dim3(256), 0, stream,
                     inputs, Wih_fw, bih_fw, bhh_fw, Wih_bw, bih_bw, bhh_bw, xpw);
  hipLaunchKernelGGL(birnn_mfma_kernel, dim3(32), dim3(128), 0, stream,
                     xpw, Whh_fw, Whh_bw, fc_W, fc_b, out);
}